// Round 11
// baseline (88.283 us; speedup 1.0000x reference)
//
#include <hip/hip_runtime.h>

// LocallyConnected2d: out[b,o,p,q] = sum_{i,kh,kw} x[b,i,2p+kh,2q+kw] * w[o,i,p,q,kh*3+kw]
// x: (8,32,64,64) f32, w: (1,32,32,31,31,9) f32, out: (8,32,31,31) f32
//
// R10 was latency-bound: stage->barrier->short-compute x4 with depth-1 prefetch
// left CUs idle on every vmcnt(0) drain (kernel ~24us vs 8.4us HBM floor).
// Now: block = (p, qg, ig, oh) = 16 q x 4 i x 16 o; ALL staging up-front
// (20 GLD4 weights + 3 GLD16 x per thread, 23-deep outstanding), ONE barrier,
// then pure-LDS compute with no further syncs. LDS = 24KB x + 40KB w = 64KB
// -> 2 blocks/CU overlap fetch/compute phases. 992 blocks.
// Weight read once device-wide (blocks partition (o,i,p,q-half) exactly).
// Partials -> d_ws coalesced + reduce kernel (atomics = 106MB RMW, R6).
// unroll 1 on compute ii-loop: bounded live set, no spill (R7 lesson).

#define NPART 246016              // 8b * 961pq * 32o floats per ig-copy
#define WS_NEED ((size_t)8 * NPART * 4)

#define GLD4(gp, lp)                                                 \
    __builtin_amdgcn_global_load_lds(                                \
        (const __attribute__((address_space(1))) void*)(gp),         \
        (__attribute__((address_space(3))) void*)(lp), 4, 0, 0)
#define GLD16(gp, lp)                                                \
    __builtin_amdgcn_global_load_lds(                                \
        (const __attribute__((address_space(1))) void*)(gp),         \
        (__attribute__((address_space(3))) void*)(lp), 16, 0, 0)

template <bool USE_WS>
__global__ __launch_bounds__(512, 2) void lc2d_kernel(const float* __restrict__ x,
                                                      const float* __restrict__ wgt,
                                                      float* __restrict__ outOrPart) {
    __shared__ float xs[6144];        // [b8][ii4][kh3][64 words] = 24 KB
    __shared__ float wlds[4 * 2560];  // [ii4][16o x 145 + pad] = 40 KB

    const int t  = threadIdx.x;
    const int ol = t & 15;            // o within half-slice
    const int bh = (t >> 4) & 1;      // b-half: b in [bh*4, bh*4+4)
    const int dq = t >> 5;            // 0..15
    const int bid = blockIdx.x;
    const int p  = bid >> 5;          // 0..30
    const int qg = (bid >> 4) & 1;
    const int ig = (bid >> 1) & 7;
    const int oh = bid & 1;           // o-half
    const int i0 = ig * 4;
    const int q0 = qg << 4;
    const int q  = q0 + dq;           // q=31 computes dup (clamped w), never stored
    const int o  = oh * 16 + ol;
    const int waveBase = t & ~63;

    // ---- stage x: full 64-word rows, 16B chunks; row r = (b*4+ii)*3+kh (256B-aligned)
#pragma unroll
    for (int j = 0; j < 3; ++j) {
        const int g  = j * 512 + t;   // 0..1535, exact
        const int r  = g >> 4;
        const int cw = (g & 15) << 2;
        const int b  = r / 12;
        const int r2 = r - b * 12;
        const int ii = r2 / 3;
        const int kh = r2 - ii * 3;
        const float* gp = x + (size_t)b * 131072 + (size_t)(i0 + ii) * 4096
                            + (size_t)(2 * p + kh) * 64 + cw;
        GLD16(gp, &xs[4 * (j * 512 + waveBase)]);
    }

    // ---- stage ALL 4 weight buffers: wlds[ii][os*145+off] <- wgt[(o0+os,i0+ii) seg]
    const int lim = (qg == 0) ? 143 : 134;   // last valid word per o-seg (pads dup, never read)
    const int pqb = p * 279 + q0 * 9;
    const int obase = oh * 16;
#pragma unroll
    for (int ii = 0; ii < 4; ++ii) {
        const size_t iw = (size_t)(i0 + ii) * 8649;
#pragma unroll
        for (int j = 0; j < 5; ++j) {
            int f = t + j * 512; f = (f < 2319) ? f : 2319;   // clamp GLOBAL only; LDS dest linear
            const int os  = f / 145;
            const int off = f - os * 145;
            const int go  = (off < lim) ? off : lim;
            GLD4(wgt + (size_t)(obase + os) * 276768 + pqb + go + iw,
                 &wlds[ii * 2560 + j * 512 + waveBase]);
        }
    }

    float acc[4];
#pragma unroll
    for (int bi = 0; bi < 4; ++bi) acc[bi] = 0.f;

    __syncthreads();                  // ONE barrier: drains all 23 staged issues

    const int wvb = ol * 145 + dq * 9;     // stride-145 across ol: bank-bijective

#pragma unroll 1                      // bounded live set -> no spill
    for (int ii = 0; ii < 4; ++ii) {
        float wv[9];
#pragma unroll
        for (int k = 0; k < 9; ++k) wv[k] = wlds[ii * 2560 + wvb + k];

        const int xb = bh * 3072 + ii * 192 + 2 * q0 + 2 * dq;
#pragma unroll
        for (int kh = 0; kh < 3; ++kh) {
#pragma unroll
            for (int bi = 0; bi < 4; ++bi) {
                const int base = xb + bi * 768 + kh * 64;
                const float2 a = *reinterpret_cast<const float2*>(&xs[base]);  // cols 2q,2q+1
                const float c1 = xs[base + 2];                                  // col 2q+2
                acc[bi] += wv[kh * 3 + 0] * a.x + wv[kh * 3 + 1] * a.y
                         + wv[kh * 3 + 2] * c1;
            }
        }
    }

    if (q <= 30) {
        const int pq = p * 31 + q;
        if (USE_WS) {
            // part[((ig*8+b)*961 + pq)*32 + o]: 16-word ol-runs -> coalesced
#pragma unroll
            for (int bi = 0; bi < 4; ++bi)
                outOrPart[((size_t)(ig * 8 + bh * 4 + bi) * 961 + pq) * 32 + o] = acc[bi];
        } else {
#pragma unroll
            for (int bi = 0; bi < 4; ++bi)
                atomicAdd(&outOrPart[(((size_t)(bh * 4 + bi) * 32 + o) * 31 + p) * 31 + q],
                          acc[bi]);
        }
    }
}

__global__ __launch_bounds__(256) void lc2d_reduce(const float* __restrict__ part,
                                                   float* __restrict__ out) {
    const int u = blockIdx.x * 256 + threadIdx.x;   // grid exactly covers 246016
    float s = 0.f;
#pragma unroll
    for (int ig = 0; ig < 8; ++ig) s += part[(size_t)ig * NPART + u];   // 8 coalesced streams
    const int o = u & 31;
    const int r = u >> 5;
    const int b = r / 961;
    const int pq = r - b * 961;
    out[(size_t)(b * 32 + o) * 961 + pq] = s;
}

extern "C" void kernel_launch(void* const* d_in, const int* in_sizes, int n_in,
                              void* d_out, int out_size, void* d_ws, size_t ws_size,
                              hipStream_t stream) {
    const float* x = (const float*)d_in[0];
    const float* w = (const float*)d_in[1];
    float* out = (float*)d_out;

    if (ws_size >= WS_NEED) {
        float* part = (float*)d_ws;
        lc2d_kernel<true><<<dim3(31 * 2 * 8 * 2), dim3(512), 0, stream>>>(x, w, part);
        lc2d_reduce<<<dim3(NPART / 256), dim3(256), 0, stream>>>(part, out);
    } else {
        hipMemsetAsync(out, 0, (size_t)out_size * sizeof(float), stream);
        lc2d_kernel<false><<<dim3(31 * 2 * 8 * 2), dim3(512), 0, stream>>>(x, w, out);
    }
}